// Round 11
// baseline (627.862 us; speedup 1.0000x reference)
//
#include <hip/hip_runtime.h>
#include <math.h>

#define B 16
#define N 2048
#define M 2048
#define BN (B * N)
#define LOG2E 1.4426950408889634f

#define CJ 128            // tile elements per LDS chunk
#define NCH (M / CJ)      // 16 chunks
#define TPB 64            // threads per block (1 wave)
#define RPT 4             // rows (or cols) per thread, STRIDED by TPB
#define RBLK (TPB * RPT)  // 256 consecutive sorted rows per WG
// sweep grid: (NCH, N/RBLK, B) = (16, 8, 16) = 2048 WGs, 2048 waves (2/SIMD)

#define EXP2F(x) __builtin_amdgcn_exp2f(x)
#define SQRTF(x) __builtin_amdgcn_sqrtf(x)

// ---------------------------------------------------------------------------
// k_sort (WGs 0..31): per-WG in-LDS bitonic sort of one cloud by x. EMD is
// permutation-invariant per cloud, so all state lives in sorted order.
// Produces packed float4 (x,y,z,|p|^2) + per-chunk x-bounds.
// WGs 32..63: folded k_init (rl=1, rr=1, rs0/rs2/t1b/ss20=0, cost=0).
// ---------------------------------------------------------------------------
__global__ __launch_bounds__(1024) void k_sort(const float* __restrict__ xyz1,
                                               const float* __restrict__ xyz2,
                                               float4* __restrict__ p1,
                                               float4* __restrict__ p2,
                                               float2* __restrict__ ib,
                                               float2* __restrict__ jb,
                                               float* __restrict__ rl0,
                                               float* __restrict__ rr0,
                                               float* __restrict__ rs0,
                                               float* __restrict__ rs2,
                                               float* __restrict__ t1b,
                                               float* __restrict__ ss20,
                                               float* __restrict__ cost) {
    const int wg = blockIdx.x;
    const int tx = threadIdx.x;
    if (wg >= 2 * B) {
        int idx = (wg - 2 * B) * 1024 + tx;  // covers BN exactly
        rl0[idx] = 1.0f;
        rr0[idx] = 1.0f;
        rs0[idx] = 0.0f;
        rs2[idx] = 0.0f;
        t1b[idx] = 0.0f;
        ss20[idx] = 0.0f;
        if (idx < B) cost[idx] = 0.0f;
        return;
    }

    __shared__ float key[2048];
    __shared__ int sidx[2048];
    const int b = wg & (B - 1);
    const bool second = wg >= B;
    const float* src = second ? xyz2 : xyz1;

    for (int t = tx; t < 2048; t += 1024) {
        key[t] = src[3 * (size_t)(b * 2048 + t)];
        sidx[t] = t;
    }
    __syncthreads();

    for (int k = 2; k <= 2048; k <<= 1) {
        for (int j = k >> 1; j > 0; j >>= 1) {
            int e = 2 * tx - (tx & (j - 1));
            int f = e + j;
            bool asc = ((e & k) == 0);
            float ke = key[e], kf = key[f];
            if ((ke > kf) == asc) {
                int ie = sidx[e], if_ = sidx[f];
                key[e] = kf;
                key[f] = ke;
                sidx[e] = if_;
                sidx[f] = ie;
            }
            __syncthreads();
        }
    }

    float4* dst = second ? p2 : p1;
    for (int t = tx; t < 2048; t += 1024) {
        int o = sidx[t];
        const float* s = src + 3 * (size_t)(b * 2048 + o);
        float x = s[0], y = s[1], z = s[2];
        dst[b * 2048 + t] = make_float4(x, y, z, fmaf(x, x, fmaf(y, y, z * z)));
    }
    if (tx < NCH) {
        float2 bb = make_float2(key[tx * CJ], key[tx * CJ + CJ - 1]);
        (second ? jb : ib)[b * NCH + tx] = bb;
    }
}

// ---------------------------------------------------------------------------
// rowsum0 (rr==1): rs[i] += sum_j exp2(c2*d2). WG-uniform underflow skip.
// Phase-batched inner loop (4 cols/step) to force cross-iteration ILP.
// ---------------------------------------------------------------------------
__global__ __launch_bounds__(TPB, 2) void k_rowsum0(const float4* __restrict__ p1,
                                                    const float4* __restrict__ p2,
                                                    const float2* __restrict__ jb,
                                                    float* __restrict__ rs,
                                                    float c2, float sqD) {
    __shared__ float4 tile4[CJ];
    const int b = blockIdx.z;
    const int tx = threadIdx.x;
    const int base = blockIdx.y * RBLK;
    const int i0 = base + tx;

    for (int t = tx; t < CJ; t += TPB) {
        int gj = b * M + blockIdx.x * CJ + t;
        float4 f = p2[gj];
        tile4[t] = make_float4(f.x, f.y, f.z, c2 * f.w);
    }
    __syncthreads();

    float2 bnd = jb[b * NCH + blockIdx.x];
    float rlo = p1[b * N + base].x;
    float rhi = p1[b * N + base + RBLK - 1].x;
    if ((bnd.x - rhi > sqD) || (rlo - bnd.y > sqD)) return;

    float X[4], Y[4], Z[4], nn[4];
#pragma unroll
    for (int r = 0; r < 4; ++r) {
        float4 f = p1[b * N + i0 + r * TPB];
        X[r] = -2.0f * c2 * f.x;
        Y[r] = -2.0f * c2 * f.y;
        Z[r] = -2.0f * c2 * f.z;
        nn[r] = c2 * f.w;
    }

    float acc[4] = {0.0f, 0.0f, 0.0f, 0.0f};
    for (int t = 0; t < CJ; t += 4) {
        float4 cc[4];
#pragma unroll
        for (int u = 0; u < 4; ++u) cc[u] = tile4[t + u];
        float g[4][4];
#pragma unroll
        for (int u = 0; u < 4; ++u)
#pragma unroll
            for (int r = 0; r < 4; ++r)
                g[u][r] = fmaf(cc[u].x, X[r],
                               fmaf(cc[u].y, Y[r], fmaf(cc[u].z, Z[r], nn[r] + cc[u].w)));
        float e[4][4];
#pragma unroll
        for (int u = 0; u < 4; ++u)
#pragma unroll
            for (int r = 0; r < 4; ++r) e[u][r] = EXP2F(g[u][r]);
#pragma unroll
        for (int u = 0; u < 4; ++u)
#pragma unroll
            for (int r = 0; r < 4; ++r) acc[r] += e[u][r];
    }
#pragma unroll
    for (int r = 0; r < 4; ++r) atomicAdd(&rs[b * N + i0 + r * TPB], acc[r]);
}

// ---------------------------------------------------------------------------
// colsum(l) + folded rl-update of level l-1 (tile phase, never skipped):
// tile elem i: rl_new = max(rl_old - (rl_old/(rs_prev+eps))*t1_in, 0);
//              a = rl_new/(rs_cur+eps); duties (y==0): rl_out, zero t1/rs.
// thread (4 strided cols j): ss2[j] += rr[j]*sum_i exp2(cS*d2)*a[i].
// WG-uniform skip after tile phase; phase-batched inner loop.
// ---------------------------------------------------------------------------
__global__ __launch_bounds__(TPB, 2) void k_colsum(const float4* __restrict__ p1,
                                                   const float4* __restrict__ p2,
                                                   const float2* __restrict__ ib,
                                                   const float* __restrict__ rl_in,
                                                   float* __restrict__ rl_out,
                                                   const float* __restrict__ rs_prev,
                                                   const float* __restrict__ rs_cur,
                                                   float* __restrict__ rs_zero,
                                                   const float* __restrict__ t1_in,
                                                   float* __restrict__ t1_zero,
                                                   const float* __restrict__ rr,
                                                   float* __restrict__ ss2_acc,
                                                   float cS, float sqD) {
    __shared__ float4 tile4[CJ];
    __shared__ float tileA[CJ];
    const int b = blockIdx.z;
    const int tx = threadIdx.x;
    const int base = blockIdx.y * RBLK;
    const int j0 = base + tx;

    for (int t = tx; t < CJ; t += TPB) {
        int gi = b * N + blockIdx.x * CJ + t;
        float4 f = p1[gi];
        float rlo = rl_in[gi];
        float ap = rlo / (rs_prev[gi] + 1e-9f);
        float rln = fmaxf(rlo - ap * t1_in[gi], 0.0f);
        float a = rln / (rs_cur[gi] + 1e-9f);
        tile4[t] = make_float4(f.x, f.y, f.z, cS * f.w);
        tileA[t] = a;
        if (blockIdx.y == 0) {
            rl_out[gi] = rln;
            t1_zero[gi] = 0.0f;
            rs_zero[gi] = 0.0f;
        }
    }
    __syncthreads();

    float2 bnd = ib[b * NCH + blockIdx.x];
    float clo = p2[b * M + base].x;
    float chi = p2[b * M + base + RBLK - 1].x;
    if ((bnd.x - chi > sqD) || (clo - bnd.y > sqD)) return;

    float X[4], Y[4], Z[4], nn[4];
#pragma unroll
    for (int r = 0; r < 4; ++r) {
        float4 f = p2[b * M + j0 + r * TPB];
        X[r] = -2.0f * cS * f.x;
        Y[r] = -2.0f * cS * f.y;
        Z[r] = -2.0f * cS * f.z;
        nn[r] = cS * f.w;
    }

    float acc[4] = {0.0f, 0.0f, 0.0f, 0.0f};
    for (int t = 0; t < CJ; t += 4) {
        float4 cc[4];
        float av[4];
#pragma unroll
        for (int u = 0; u < 4; ++u) {
            cc[u] = tile4[t + u];
            av[u] = tileA[t + u];
        }
        float g[4][4];
#pragma unroll
        for (int u = 0; u < 4; ++u)
#pragma unroll
            for (int r = 0; r < 4; ++r)
                g[u][r] = fmaf(cc[u].x, X[r],
                               fmaf(cc[u].y, Y[r], fmaf(cc[u].z, Z[r], nn[r] + cc[u].w)));
        float e[4][4];
#pragma unroll
        for (int u = 0; u < 4; ++u)
#pragma unroll
            for (int r = 0; r < 4; ++r) e[u][r] = EXP2F(g[u][r]);
#pragma unroll
        for (int u = 0; u < 4; ++u)
#pragma unroll
            for (int r = 0; r < 4; ++r) acc[r] = fmaf(e[u][r], av[u], acc[r]);
    }
#pragma unroll
    for (int r = 0; r < 4; ++r)
        atomicAdd(&ss2_acc[b * M + j0 + r * TPB], acc[r] * rr[b * M + j0 + r * TPB]);
}

// ---------------------------------------------------------------------------
// Level-9 colsum shortcut part 1 (exp==1): S[b] = sum_i a_i (+ level-8 rl
// fold). Part 2 (ss2 = rr*S) is folded into fused MODE2's tile phase.
// ---------------------------------------------------------------------------
__global__ __launch_bounds__(256) void k_suma(const float* __restrict__ rl_in,
                                              float* __restrict__ rl_out,
                                              const float* __restrict__ rs_prev,
                                              const float* __restrict__ rs_cur,
                                              const float* __restrict__ t1_in,
                                              float* __restrict__ S) {
    __shared__ float red[4];
    const int b = blockIdx.x;
    const int tx = threadIdx.x;
    float s = 0.0f;
#pragma unroll
    for (int k = 0; k < N / 256; ++k) {
        int gi = b * N + k * 256 + tx;
        float rlo = rl_in[gi];
        float ap = rlo / (rs_prev[gi] + 1e-9f);
        float rln = fmaxf(rlo - ap * t1_in[gi], 0.0f);
        rl_out[gi] = rln;
        s += rln / (rs_cur[gi] + 1e-9f);
    }
#pragma unroll
    for (int off = 32; off > 0; off >>= 1)
        s += __shfl_down(s, off, 64);
    if ((tx & 63) == 0) red[tx >> 6] = s;
    __syncthreads();
    if (tx == 0) S[b] = red[0] + red[1] + red[2] + red[3];
}

// ---------------------------------------------------------------------------
// Fused finrow(l) + rowsum(l+1). 4 strided rows/thread; phase-batched loop.
// tile elem j (never skipped): sv = ss2_in[j] (MODE0/1) or rr*S[b] (MODE2);
//   s=min(rr/(sv+eps),1); q=rr*s; rrn=max(rr-sv*s,0);
//   duties (y==0, MODE!=2): rr_out[j]=rrn, zero ss2_zero[j].
// MODE 0 (l=0..7): cS=c2[l+1]; en=exp2(arg); el=en^4; WG-uniform skip.
// MODE 1 (l=8): el=exp2(arg); rs+=rrn unconditional -> never skip.
// MODE 2 (l=9): el=1; never skip.
// sd = sqrt(|arg|); dist = sd*rsq (rsq=rsqrt(|cS|), epilogue).
// ---------------------------------------------------------------------------
template <int MODE>
__global__ __launch_bounds__(TPB, 2) void k_fused(const float4* __restrict__ p1,
                                                  const float4* __restrict__ p2,
                                                  const float2* __restrict__ jb,
                                                  const float* __restrict__ rr_in,
                                                  float* __restrict__ rr_out,
                                                  const float* __restrict__ ss2_in,
                                                  float* __restrict__ ss2_zero,
                                                  const float* __restrict__ Sb,
                                                  const float* __restrict__ rl_new,
                                                  const float* __restrict__ rs_cur,
                                                  float* __restrict__ rs_next,
                                                  float* __restrict__ t1_acc,
                                                  float* __restrict__ cost,
                                                  float cS, float rsq, float sqD) {
    __shared__ float4 tile4[CJ];  // xj, yj, zj, q
    __shared__ float2 tile2[CJ];  // rrn, cS*nj
    const int b = blockIdx.z;
    const int tx = threadIdx.x;
    const int base = blockIdx.y * RBLK;
    const int i0 = base + tx;

    for (int t = tx; t < CJ; t += TPB) {
        int gj = b * M + blockIdx.x * CJ + t;
        float4 f = p2[gj];
        float rrv = rr_in[gj];
        float sv = (MODE == 2) ? rrv * Sb[b] : ss2_in[gj];
        float s = fminf(rrv / (sv + 1e-9f), 1.0f);
        float q = rrv * s;
        float rrn = fmaxf(rrv - sv * s, 0.0f);
        tile4[t] = make_float4(f.x, f.y, f.z, q);
        tile2[t] = make_float2(rrn, cS * f.w);
        if (MODE != 2 && blockIdx.y == 0) {
            rr_out[gj] = rrn;
            ss2_zero[gj] = 0.0f;
        }
    }
    __syncthreads();

    if (MODE == 0) {
        float2 bnd = jb[b * NCH + blockIdx.x];
        float rlo = p1[b * N + base].x;
        float rhi = p1[b * N + base + RBLK - 1].x;
        if ((bnd.x - rhi > sqD) || (rlo - bnd.y > sqD)) return;  // WG-uniform
    }

    float X[4], Y[4], Z[4], nn[4];
#pragma unroll
    for (int r = 0; r < 4; ++r) {
        float4 f = p1[b * N + i0 + r * TPB];
        X[r] = -2.0f * cS * f.x;
        Y[r] = -2.0f * cS * f.y;
        Z[r] = -2.0f * cS * f.z;
        nn[r] = cS * f.w;
    }

    float T1[4] = {0, 0, 0, 0}, T2[4] = {0, 0, 0, 0}, rsv[4] = {0, 0, 0, 0};
    for (int t = 0; t < CJ; t += 4) {
        float4 cc[4];
        float2 rn[4];
#pragma unroll
        for (int u = 0; u < 4; ++u) {
            cc[u] = tile4[t + u];
            rn[u] = tile2[t + u];
        }
        float g[4][4];
#pragma unroll
        for (int u = 0; u < 4; ++u)
#pragma unroll
            for (int r = 0; r < 4; ++r)
                g[u][r] = fmaf(cc[u].x, X[r],
                               fmaf(cc[u].y, Y[r], fmaf(cc[u].z, Z[r], nn[r] + rn[u].y)));
        float sd[4][4];
#pragma unroll
        for (int u = 0; u < 4; ++u)
#pragma unroll
            for (int r = 0; r < 4; ++r) sd[u][r] = SQRTF(fabsf(g[u][r]));
        if (MODE == 0) {
            float e[4][4];
#pragma unroll
            for (int u = 0; u < 4; ++u)
#pragma unroll
                for (int r = 0; r < 4; ++r) e[u][r] = EXP2F(g[u][r]);
#pragma unroll
            for (int u = 0; u < 4; ++u)
#pragma unroll
                for (int r = 0; r < 4; ++r) {
                    float e2 = e[u][r] * e[u][r];
                    float w = (e2 * e2) * cc[u].w;
                    T1[r] += w;
                    T2[r] = fmaf(w, sd[u][r], T2[r]);
                    rsv[r] = fmaf(e[u][r], rn[u].x, rsv[r]);
                }
        } else if (MODE == 1) {
            float e[4][4];
#pragma unroll
            for (int u = 0; u < 4; ++u)
#pragma unroll
                for (int r = 0; r < 4; ++r) e[u][r] = EXP2F(g[u][r]);
#pragma unroll
            for (int u = 0; u < 4; ++u)
#pragma unroll
                for (int r = 0; r < 4; ++r) {
                    float w = e[u][r] * cc[u].w;
                    T1[r] += w;
                    T2[r] = fmaf(w, sd[u][r], T2[r]);
                    rsv[r] += rn[u].x;
                }
        } else {
#pragma unroll
            for (int u = 0; u < 4; ++u)
#pragma unroll
                for (int r = 0; r < 4; ++r) {
                    T1[r] += cc[u].w;
                    T2[r] = fmaf(cc[u].w, sd[u][r], T2[r]);
                }
        }
    }

    const int gi0 = b * N + i0;
    if (MODE != 2) {
#pragma unroll
        for (int r = 0; r < 4; ++r) {
            atomicAdd(&t1_acc[gi0 + r * TPB], T1[r]);
            atomicAdd(&rs_next[gi0 + r * TPB], rsv[r]);
        }
    }

    float contrib = 0.0f;
#pragma unroll
    for (int r = 0; r < 4; ++r) {
        float a = rl_new[gi0 + r * TPB] / (rs_cur[gi0 + r * TPB] + 1e-9f);
        contrib = fmaf(a, T2[r], contrib);
    }
    contrib *= rsq;
#pragma unroll
    for (int off = 32; off > 0; off >>= 1)
        contrib += __shfl_down(contrib, off, 64);
    if (tx == 0) atomicAdd(&cost[b], contrib);
}

extern "C" void kernel_launch(void* const* d_in, const int* in_sizes, int n_in,
                              void* d_out, int out_size, void* d_ws, size_t ws_size,
                              hipStream_t stream) {
    const float* xyz1 = (const float*)d_in[0];
    const float* xyz2 = (const float*)d_in[1];
    float* cost = (float*)d_out;

    float* ws = (float*)d_ws;
    float* rl[2] = {ws + 0 * BN, ws + 1 * BN};
    float* rr[2] = {ws + 2 * BN, ws + 3 * BN};
    float* rs[3] = {ws + 4 * BN, ws + 5 * BN, ws + 6 * BN};
    float* ss2b[2] = {ws + 7 * BN, ws + 8 * BN};
    float* t1[2] = {ws + 9 * BN, ws + 10 * BN};
    float4* p1 = (float4*)(ws + 11 * BN);
    float4* p2 = (float4*)(ws + 15 * BN);
    float* S = ws + 19 * BN;
    float2* ib = (float2*)(ws + 19 * BN + 64);   // B*NCH = 256 float2
    float2* jb = (float2*)(ws + 19 * BN + 64 + 512);

    static const float levels[10] = {-16384.0f, -4096.0f, -1024.0f, -256.0f,
                                     -64.0f,    -16.0f,   -4.0f,    -1.0f,
                                     -0.25f,    0.0f};
    float c2[10], sqD[10];
    for (int l = 0; l < 10; ++l) {
        c2[l] = levels[l] * LOG2E;
        sqD[l] = (l < 9) ? sqrtf(150.0f / fabsf(c2[l])) : 1e30f;
    }

    dim3 grid(NCH, N / RBLK, B);  // (16, 8, 16) = 2048 WGs, 2048 waves
    dim3 blk(TPB);
    dim3 b256(256);

    // 32 sort WGs + 32 init WGs in one launch
    k_sort<<<dim3(2 * B + 32), dim3(1024), 0, stream>>>(
        xyz1, xyz2, p1, p2, ib, jb, rl[0], rr[0], rs[0], rs[2], t1[1], ss2b[0], cost);
    k_rowsum0<<<grid, blk, 0, stream>>>(p1, p2, jb, rs[0], c2[0], sqD[0]);

    for (int l = 0; l < 10; ++l) {
        int p = l & 1;
        if (l < 9) {
            // colsum(l): reads rs[(l+2)%3] (prev), rs[l%3] (cur), t1[1-p];
            // zeroes rs[(l+1)%3], t1[p]; rl[p]->rl[1-p]; accum ss2b[p].
            k_colsum<<<grid, blk, 0, stream>>>(
                p1, p2, ib, rl[p], rl[1 - p], rs[(l + 2) % 3], rs[l % 3],
                rs[(l + 1) % 3], t1[1 - p], t1[p], rr[p], ss2b[p], c2[l], sqD[l]);
        } else {
            k_suma<<<dim3(B), b256, 0, stream>>>(
                rl[p], rl[1 - p], rs[(l + 2) % 3], rs[l % 3], t1[1 - p], S);
        }

        // fused(l): rr[p]->rr[1-p]; reads ss2b[p] (MODE2: rr*S inline),
        // zeroes ss2b[1-p]; reads rl[1-p], rs[l%3]; accum rs[(l+1)%3],
        // t1[p], cost.
        if (l <= 7) {
            float cS = c2[l + 1];
            float rsq = 1.0f / sqrtf(fabsf(cS));
            k_fused<0><<<grid, blk, 0, stream>>>(
                p1, p2, jb, rr[p], rr[1 - p], ss2b[p], ss2b[1 - p], nullptr,
                rl[1 - p], rs[l % 3], rs[(l + 1) % 3], t1[p], cost, cS, rsq,
                sqD[l + 1]);
        } else if (l == 8) {
            float cS = c2[8];
            float rsq = 1.0f / sqrtf(fabsf(cS));
            k_fused<1><<<grid, blk, 0, stream>>>(
                p1, p2, jb, rr[p], rr[1 - p], ss2b[p], ss2b[1 - p], nullptr,
                rl[1 - p], rs[l % 3], rs[(l + 1) % 3], t1[p], cost, cS, rsq, 1e30f);
        } else {
            k_fused<2><<<grid, blk, 0, stream>>>(
                p1, p2, jb, rr[p], rr[1 - p], ss2b[p], ss2b[1 - p], S,
                rl[1 - p], rs[l % 3], rs[(l + 1) % 3], t1[p], cost, 1.0f, 1.0f,
                1e30f);
        }
    }
}